// Round 5
// baseline (184.613 us; speedup 1.0000x reference)
//
#include <hip/hip_runtime.h>
#include <cstdint>

#define NN 16000
#define KK 16
#define FIN 32
#define HH 64
#define NE (NN*KK)
#define GG 64
#define NCELL (GG*GG)

#define KNNB 250                 // knn blocks: 64 nodes/block (4 lanes/node)
#define GEMM1B (NN*16/256)       // 1000 gemm1 blocks

// ---------------------------------------------------------------- front: prep + hist + scan + scatter (one block)
// Single 1024-thread block replaces memset+prep+scan+scatter (4 enqueues ->
// 1): histogram and cursor live in LDS, prefix-scan code is the proven
// scan_kernel body reading LDS counts. Scatter order within a cell is
// nondeterministic (atomic) exactly as before - knn selection is exact-key
// based so any within-cell order yields identical results.
__global__ __launch_bounds__(1024) void front_kernel(const float* __restrict__ c,
                                                     float4* __restrict__ pack,
                                                     unsigned* __restrict__ cellid,
                                                     unsigned* __restrict__ cstart,
                                                     float4* __restrict__ sorted,
                                                     int* __restrict__ sid,
                                                     unsigned* __restrict__ gmm) {
#pragma clang fp contract(off)
  __shared__ unsigned hist[NCELL];       // counts -> cursors (16 KB)
  __shared__ unsigned wsum[16];
  const int tid = threadIdx.x;
  const int lane = tid & 63, wv = tid >> 6;
  if (tid == 0) { gmm[0] = 0x7F800000u; gmm[1] = 0u; }  // min=+inf bits, max=0
  for (int j = tid; j < NCELL; j += 1024) hist[j] = 0;
  __syncthreads();

  // ---- phase 1: pack + cellid + LDS histogram
  for (int i = tid; i < NN; i += 1024) {
    float xv = c[2*i], yv = c[2*i+1];
    float xx = xv * xv;            // round(x^2)  (no fma: contract off)
    float yy = yv * yv;            // round(y^2)
    float sq = xx + yy;            // round(xx+yy)
    pack[i] = make_float4(xv, yv, sq, __uint_as_float((unsigned)i));
    int cx = (int)(xv * GG); cx = cx > GG-1 ? GG-1 : (cx < 0 ? 0 : cx);
    int cy = (int)(yv * GG); cy = cy > GG-1 ? GG-1 : (cy < 0 ? 0 : cy);
    unsigned cell = (unsigned)(cy * GG + cx);
    cellid[i] = cell;
    atomicAdd(&hist[cell], 1u);
  }
  __syncthreads();

  // ---- phase 2: prefix scan (proven scan_kernel body, counts from LDS)
  unsigned c0 = hist[tid*4+0], c1 = hist[tid*4+1], c2 = hist[tid*4+2], c3 = hist[tid*4+3];
  unsigned s = c0 + c1 + c2 + c3;
  unsigned v = s;
#pragma unroll
  for (int off = 1; off < 64; off <<= 1) {
    unsigned u = __shfl_up(v, off, 64);
    if (lane >= off) v += u;
  }
  if (lane == 63) wsum[wv] = v;
  __syncthreads();
  if (wv == 0) {
    unsigned t = (lane < 16) ? wsum[lane] : 0u;
    unsigned vv = t;
#pragma unroll
    for (int off = 1; off < 16; off <<= 1) {
      unsigned u = __shfl_up(vv, off, 64);
      if (lane >= off) vv += u;
    }
    if (lane < 16) wsum[lane] = vv - t;            // exclusive
  }
  __syncthreads();
  unsigned b = wsum[wv] + v - s;
  cstart[tid*4+0] = b; unsigned u0 = b; b += c0;
  cstart[tid*4+1] = b; unsigned u1 = b; b += c1;
  cstart[tid*4+2] = b; unsigned u2 = b; b += c2;
  cstart[tid*4+3] = b; unsigned u3 = b; b += c3;
  if (tid == 1023) cstart[NCELL] = b;              // == NN
  __syncthreads();                                 // all reads of hist done
  hist[tid*4+0] = u0; hist[tid*4+1] = u1;          // hist becomes cursor
  hist[tid*4+2] = u2; hist[tid*4+3] = u3;
  __syncthreads();

  // ---- phase 3: scatter into cell order (LDS cursors)
  for (int i = tid; i < NN; i += 1024) {
    unsigned p = atomicAdd(&hist[cellid[i]], 1u);
    sorted[p] = pack[i];                           // .w carries original index bits
    sid[p] = i;
  }
}

// ---------------------------------------------------------------- knn (code-minimized) + gemm1 backfill
// R4 post-mortem: knn time (~43us) is invariant to data placement (global /
// pipelined / LDS-staged all equal) with VALUBusy 13-15% -> theory:
// instruction-cache thrash. Old versions inlined the ~110-instr insert
// network at 60+ sites (~50KB hot code vs 32KB I$). This version instantiates
// scanSpan at exactly 3 sites (all runtime '#pragma unroll 1' loops) x 2
// process copies = 6 copies (~5KB). Candidate set, stop test, insert
// arithmetic, merge, epilogue are bit-identical to the proven R2 kernel
// (selection is scan-order independent; keys unique via index bits).
__global__ __launch_bounds__(256) void knn_gemm1_kernel(const float4* __restrict__ sorted,
                                                        const unsigned* __restrict__ cstart,
                                                        const float* __restrict__ c,
                                                        int* __restrict__ nbr,
                                                        float* __restrict__ de,
                                                        unsigned* __restrict__ gmm,
                                                        const float* __restrict__ xa_,
                                                        const float* __restrict__ w1,
                                                        float* __restrict__ xw1) {
#pragma clang fp contract(off)
  if (blockIdx.x >= KNNB) {
    // ---- gemm1: xw1 = x @ W1, KIN=32, 4 features/thread (R1-verbatim, proven)
    int gid = (blockIdx.x - KNNB) * 256 + threadIdx.x;   // NN*16 total
    int i = gid >> 4, fq = gid & 15;
    const float4* ar = (const float4*)(xa_ + i * FIN);
    float4 A[FIN/4];
#pragma unroll
    for (int qq = 0; qq < FIN/4; ++qq) A[qq] = ar[qq];
    float4 acc = make_float4(0.f, 0.f, 0.f, 0.f);
#pragma unroll
    for (int k = 0; k < FIN; ++k) {
      float av = ((const float*)A)[k];
      float4 wv4 = *(const float4*)(w1 + k*HH + 4*fq);
      acc.x = fmaf(av, wv4.x, acc.x);
      acc.y = fmaf(av, wv4.y, acc.y);
      acc.z = fmaf(av, wv4.z, acc.z);
      acc.w = fmaf(av, wv4.w, acc.w);
    }
    *(float4*)(xw1 + i*HH + 4*fq) = acc;
    return;
  }

  const int g = blockIdx.x * 256 + threadIdx.x;
  const int t = g >> 2;                            // sorted node index
  const int q = g & 3;                             // quad lane
  const int lane = threadIdx.x & 63;
  const float4 me = sorted[t];
  const int myid = (int)__float_as_uint(me.w);
  const float h = 1.0f / GG;                       // exact 2^-6
  int cx = (int)(me.x * GG); cx = cx > GG-1 ? GG-1 : (cx < 0 ? 0 : cx);
  int cy = (int)(me.y * GG); cy = cy > GG-1 ? GG-1 : (cy < 0 ? 0 : cy);

  unsigned long long kd[KK];
#pragma unroll
  for (int m = 0; m < KK; ++m) kd[m] = ~0ull;

  auto process = [&](float4 cand) {
    int j = (int)__float_as_uint(cand.w);
    float xprod = me.x * cand.x;                       // round(x_i*x_j)
    float dot   = __builtin_fmaf(me.y, cand.y, xprod); // BLAS K=2 fma
    float S     = me.z + cand.z;                       // round(sq_i+sq_j)
    float twod  = dot + dot;                           // exact *2
    float d2    = S - twod;                            // one rounding
    unsigned ub = __float_as_uint(d2);
    ub = (ub & 0x80000000u) ? ~ub : (ub | 0x80000000u);
    unsigned long long key = ((unsigned long long)ub << 32) | (unsigned)j;
    if (j != myid && key < kd[KK-1]) {
      unsigned long long ck = key;
#pragma unroll
      for (int m = 0; m < KK; ++m) {
        bool sw = ck < kd[m];
        unsigned long long lo = sw ? ck : kd[m];
        unsigned long long hi = sw ? kd[m] : ck;
        kd[m] = lo; ck = hi;
      }
    }
  };
  // 2-deep pipelined span scan; instantiated at exactly 3 call sites
  auto scanSpan = [&](unsigned p0, unsigned p1) {
    unsigned pp = p0 + (unsigned)q;
    if (pp >= p1) return;
    float4 cur = sorted[pp];
    unsigned pn = pp + 4;
#pragma unroll 1
    while (pn < p1) {
      float4 nxt = sorted[pn];
      process(cur);
      cur = nxt;
      pn += 4;
    }
    process(cur);
  };

  // ---- initial 5x5 rect (site 1): row bounds software-pipelined
  int lxa = cx-2 < 0 ? 0 : cx-2;
  int lxb = cx+2 > GG-1 ? GG-1 : cx+2;
  int lya = cy-2 < 0 ? 0 : cy-2;
  int lyb = cy+2 > GG-1 ? GG-1 : cy+2;
  {
    unsigned b0 = cstart[lya*GG + lxa];
    unsigned b1 = cstart[lya*GG + lxb + 1];
#pragma unroll 1
    for (int y = lya; y <= lyb; ++y) {
      unsigned n0 = 0, n1 = 0;
      if (y < lyb) { n0 = cstart[(y+1)*GG + lxa]; n1 = cstart[(y+1)*GG + lxb + 1]; }
      scanSpan(b0, b1);
      b0 = n0; b1 = n1;
    }
  }

  // ---- ring expansion with exact count-based stop (validated R9)
  int R = 2;
  while (true) {
    bool whole = (lxa <= 0) && (lxb >= GG-1) && (lya <= 0) && (lyb >= GG-1);
    bool done = whole;
    if (!done) {
      float edge = 1e30f;
      if (lxa > 0)    edge = fminf(edge, me.x - (float)lxa * h);
      if (lxb < GG-1) edge = fminf(edge, (float)(lxb+1) * h - me.x);
      if (lya > 0)    edge = fminf(edge, me.y - (float)lya * h);
      if (lyb < GG-1) edge = fminf(edge, (float)(lyb+1) * h - me.y);
      float lim = edge * edge - 1e-5f;             // margin >> Gram noise (~1e-6)
      if (lim > 0.0f) {
        unsigned lb = __float_as_uint(lim) | 0x80000000u;   // map(lim), lim>0
        int cle = 0;
#pragma unroll
        for (int m = 0; m < KK; ++m) cle += ((unsigned)(kd[m] >> 32) <= lb) ? 1 : 0;
        cle += __shfl_xor(cle, 1, 64);
        cle += __shfl_xor(cle, 2, 64);
        done = cle >= KK;
      }
    }
    if (done) break;
    ++R;
    int nxa = cx-R < 0 ? 0 : cx-R;
    int nxb = cx+R > GG-1 ? GG-1 : cx+R;
    int nya = cy-R < 0 ? 0 : cy-R;
    int nyb = cy+R > GG-1 ? GG-1 : cy+R;
    // new top/bottom rows (site 2)
#pragma unroll 1
    for (int rr = 0; rr < 2; ++rr) {
      int y = rr ? nyb : nya;
      bool has = rr ? (nyb > lyb) : (nya < lya);
      if (has) {
        unsigned p0 = cstart[y*GG + nxa];
        unsigned p1 = cstart[y*GG + nxb + 1];
        scanSpan(p0, p1);
      }
    }
    // new left/right columns (site 3): per-cell spans, bounds pipelined
#pragma unroll 1
    for (int ss = 0; ss < 2; ++ss) {
      int xcol = ss ? nxb : nxa;
      bool has = ss ? (nxb > lxb) : (nxa < lxa);
      if (has) {
        unsigned b0 = cstart[lya*GG + xcol];
        unsigned b1 = cstart[lya*GG + xcol + 1];
#pragma unroll 1
        for (int y = lya; y <= lyb; ++y) {
          unsigned n0 = 0, n1 = 0;
          if (y < lyb) { n0 = cstart[(y+1)*GG + xcol]; n1 = cstart[(y+1)*GG + xcol + 1]; }
          scanSpan(b0, b1);
          b0 = n0; b1 = n1;
        }
      }
    }
    lxa = nxa; lxb = nxb; lya = nya; lyb = nyb;
  }

  // ---- merge 4 sorted per-lane lists -> global top-16 (keys unique via j bits)
  unsigned res[4];
#pragma unroll 1
  for (int r = 0; r < KK; ++r) {
    unsigned long long md = kd[0];
    unsigned long long m1 = __shfl_xor(md, 1, 64); md = m1 < md ? m1 : md;
    unsigned long long m2 = __shfl_xor(md, 2, 64); md = m2 < md ? m2 : md;
    if (kd[0] == md) {                              // unique winner lane pops
#pragma unroll
      for (int m = 0; m < KK-1; ++m) kd[m] = kd[m+1];
      kd[KK-1] = ~0ull;
    }
    if ((r >> 2) == q) res[r & 3] = (unsigned)(md & 0xFFFFFFFFull);
  }

  // ---- write nbr + edge epilogue (identical ops to passing rounds)
  int4 w4; w4.x = (int)res[0]; w4.y = (int)res[1]; w4.z = (int)res[2]; w4.w = (int)res[3];
  *(int4*)(nbr + myid*KK + 4*q) = w4;
  unsigned bmin = 0xFFFFFFFFu, bmax = 0u;
#pragma unroll
  for (int e = 0; e < 4; ++e) {
    int j = (int)res[e];
    float dx = me.x - c[2*j];
    float dy = me.y - c[2*j+1];
    float xx = dx * dx;
    float yy = dy * dy;
    float d  = __builtin_sqrtf(xx + yy);
    de[myid*KK + 4*q + e] = d;
    unsigned bb = __float_as_uint(d);               // d >= 0: bit order == float order
    bmin = bmin < bb ? bmin : bb;
    bmax = bmax > bb ? bmax : bb;
  }
#pragma unroll
  for (int off = 32; off > 0; off >>= 1) {
    unsigned ob = __shfl_xor(bmin, off, 64);
    bmin = bmin < ob ? bmin : ob;
    unsigned oB = __shfl_xor(bmax, off, 64);
    bmax = bmax > oB ? bmax : oB;
  }
  if (lane == 0) {
    atomicMin(&gmm[0], bmin);
    atomicMax(&gmm[1], bmax);
  }
}

// ---------------------------------------------------------------- ew + deg + dis
__global__ __launch_bounds__(256) void ewdeg_kernel(const unsigned* __restrict__ gmm,
                                                    float* __restrict__ de,   // in: d, out: ew
                                                    float* __restrict__ dis) {
#pragma clang fp contract(off)
  int i = blockIdx.x * 256 + threadIdx.x;
  if (i >= NN) return;
  float mx  = __uint_as_float(gmm[1]);
  float rng = mx - __uint_as_float(gmm[0]);
  float deg = 0.0f;                         // edges first, self-loop last (segment_sum order)
  float4* dp = (float4*)(de + i*KK);
#pragma unroll
  for (int qq = 0; qq < 4; ++qq) {
    float4 v = dp[qq];
    float e0 = (mx - v.x) / rng;
    float e1 = (mx - v.y) / rng;
    float e2 = (mx - v.z) / rng;
    float e3 = (mx - v.w) / rng;
    deg = deg + e0; deg = deg + e1;
    deg = deg + e2; deg = deg + e3;
    dp[qq] = make_float4(e0, e1, e2, e3);
  }
  deg = deg + 1.0f;                         // self-loop weight 1, added last
  dis[i] = 1.0f / __builtin_sqrtf(deg);     // deg >= 1
}

// ---------------------------------------------------------------- agg1 + relu + gemm2 fused
// h1 row lives in registers (one float/lane); gemm2 via 64 shfl broadcasts,
// ascending-k fmaf order -> bit-identical xw2.
__global__ __launch_bounds__(256) void agg_gemm2_kernel(const float* __restrict__ xw,
                                                        const int* __restrict__ nbr,
                                                        const float* __restrict__ ew,
                                                        const float* __restrict__ dis,
                                                        const float* __restrict__ b,
                                                        const int* __restrict__ sid,
                                                        const float* __restrict__ w2,
                                                        float* __restrict__ xw2) {
  int wv = threadIdx.x >> 6, lane = threadIdx.x & 63;
  int i = sid[(blockIdx.x << 2) + wv];
  float di = dis[i];
  float acc = 0.0f;
#pragma unroll 4
  for (int k = 0; k < KK; ++k) {
    int s = nbr[i*KK + k];
    float coef = (dis[s] * ew[i*KK + k]) * di;   // (dis[s]*w)*dis[t]
    acc = fmaf(coef, xw[s*HH + lane], acc);
  }
  acc = fmaf(di * di, xw[i*HH + lane], acc);     // self loop last
  float hv = fmaxf(acc + b[lane], 0.0f);         // h1[i][lane]
  float acc2 = 0.0f;
#pragma unroll 16
  for (int k = 0; k < HH; ++k) {
    float hk = __shfl(hv, k, 64);
    acc2 = fmaf(hk, w2[k*HH + lane], acc2);
  }
  xw2[i*HH + lane] = acc2;
}

// ---------------------------------------------------------------- agg2 + relu + fc (final)
__global__ __launch_bounds__(256) void agg_fc_kernel(const float* __restrict__ xw,
                                                     const int* __restrict__ nbr,
                                                     const float* __restrict__ ew,
                                                     const float* __restrict__ dis,
                                                     const float* __restrict__ b,
                                                     const float* __restrict__ wfc,
                                                     const float* __restrict__ bfc,
                                                     const int* __restrict__ sid,
                                                     float* __restrict__ out) {
  int wv = threadIdx.x >> 6, lane = threadIdx.x & 63;
  int i = sid[(blockIdx.x << 2) + wv];
  float di = dis[i];
  float acc = 0.0f;
#pragma unroll 4
  for (int k = 0; k < KK; ++k) {
    int s = nbr[i*KK + k];
    float coef = (dis[s] * ew[i*KK + k]) * di;
    acc = fmaf(coef, xw[s*HH + lane], acc);
  }
  acc = fmaf(di * di, xw[i*HH + lane], acc);
  float v = fmaxf(acc + b[lane], 0.0f);             // h2 feature
  float p = v * wfc[lane];                          // h2 @ Wfc  (F_OUT = 1)
#pragma unroll
  for (int off = 32; off > 0; off >>= 1) p = p + __shfl_xor(p, off, 64);
  if (lane == 0) out[i] = p + bfc[0];
}

// ---------------------------------------------------------------- launch
extern "C" void kernel_launch(void* const* d_in, const int* in_sizes, int n_in,
                              void* d_out, int out_size, void* d_ws, size_t ws_size,
                              hipStream_t stream) {
  (void)in_sizes; (void)n_in; (void)out_size; (void)ws_size;
  const float* x   = (const float*)d_in[0];
  const float* c   = (const float*)d_in[1];
  const float* W1  = (const float*)d_in[2];
  const float* b1  = (const float*)d_in[3];
  const float* W2  = (const float*)d_in[4];
  const float* b2  = (const float*)d_in[5];
  const float* Wfc = (const float*)d_in[6];
  const float* bfc = (const float*)d_in[7];
  float* out = (float*)d_out;

  char* ws = (char*)d_ws;
  size_t off = 0;
  auto alloc = [&](size_t bytes) -> void* {
    void* p = ws + off;
    off += (bytes + 255) & ~size_t(255);
    return p;
  };
  float4*   pack   = (float4*)  alloc(NN * sizeof(float4));       // 256 KB
  float4*   sorted = (float4*)  alloc(NN * sizeof(float4));       // 256 KB
  unsigned* cstart = (unsigned*)alloc((NCELL+1) * sizeof(unsigned));
  unsigned* cellid = (unsigned*)alloc(NN * sizeof(unsigned));     // 64 KB
  int*      sid    = (int*)     alloc(NN * sizeof(int));          // 64 KB
  int*      nbr    = (int*)     alloc(NE * sizeof(int));          // 1 MB
  float*    ew     = (float*)   alloc(NE * sizeof(float));        // 1 MB (d then ew in-place)
  float*    dis    = (float*)   alloc(NN * sizeof(float));        // 64 KB
  unsigned* gmm    = (unsigned*)alloc(2 * sizeof(unsigned));
  float*    xw1    = (float*)   alloc(NN * HH * sizeof(float));   // 4 MB
  float*    xw2    = (float*)   alloc(NN * HH * sizeof(float));   // 4 MB

  const int NB = (NN + 255) / 256;
  front_kernel     <<<1,   1024, 0, stream>>>(c, pack, cellid, cstart, sorted, sid, gmm);
  knn_gemm1_kernel <<<KNNB + GEMM1B, 256, 0, stream>>>(sorted, cstart, c, nbr, ew, gmm,
                                                       x, W1, xw1);
  ewdeg_kernel     <<<NB,   256, 0, stream>>>(gmm, ew, dis);
  agg_gemm2_kernel <<<NN/4, 256, 0, stream>>>(xw1, nbr, ew, dis, b1, sid, W2, xw2);
  agg_fc_kernel    <<<NN/4, 256, 0, stream>>>(xw2, nbr, ew, dis, b2, Wfc, bfc, sid, out);
}

// Round 6
// 171.030 us; speedup vs baseline: 1.0794x; 1.0794x over previous
//
#include <hip/hip_runtime.h>
#include <cstdint>

#define NN 16000
#define KK 16
#define FIN 32
#define HH 64
#define NE (NN*KK)
#define GG 64
#define NCELL (GG*GG)

#define KNNB 250                 // knn blocks: 64 nodes/block (4 lanes/node)
#define GEMM1B (NN*16/256)       // 1000 gemm1 blocks

// ---------------------------------------------------------------- prep + count
__global__ __launch_bounds__(256) void prep_count_kernel(const float* __restrict__ c,
                                                         float4* __restrict__ pack,
                                                         unsigned* __restrict__ cellid,
                                                         unsigned* __restrict__ cnt,
                                                         unsigned* __restrict__ gmm) {
#pragma clang fp contract(off)
  int i = blockIdx.x * 256 + threadIdx.x;
  if (i == 0) { gmm[0] = 0x7F800000u; gmm[1] = 0u; }  // min=+inf bits, max=0 (d>=0)
  if (i >= NN) return;
  float xv = c[2*i], yv = c[2*i+1];
  float xx = xv * xv;            // round(x^2)  (no fma: contract off)
  float yy = yv * yv;            // round(y^2)
  float sq = xx + yy;            // round(xx+yy)
  pack[i] = make_float4(xv, yv, sq, __uint_as_float((unsigned)i));
  int cx = (int)(xv * GG); cx = cx > GG-1 ? GG-1 : (cx < 0 ? 0 : cx);
  int cy = (int)(yv * GG); cy = cy > GG-1 ? GG-1 : (cy < 0 ? 0 : cy);
  unsigned cell = (unsigned)(cy * GG + cx);
  cellid[i] = cell;
  atomicAdd(&cnt[cell], 1u);
}

// ---------------------------------------------------------------- prefix scan (single block, wave-shuffle)
__global__ __launch_bounds__(1024) void scan_kernel(const unsigned* __restrict__ cnt,
                                                    unsigned* __restrict__ cstart,
                                                    unsigned* __restrict__ cursor) {
  __shared__ unsigned wsum[16];
  int tid = threadIdx.x;
  int lane = tid & 63, wv = tid >> 6;
  unsigned c0 = cnt[tid*4+0], c1 = cnt[tid*4+1], c2 = cnt[tid*4+2], c3 = cnt[tid*4+3];
  unsigned s = c0 + c1 + c2 + c3;
  unsigned v = s;
#pragma unroll
  for (int off = 1; off < 64; off <<= 1) {
    unsigned u = __shfl_up(v, off, 64);
    if (lane >= off) v += u;
  }
  if (lane == 63) wsum[wv] = v;
  __syncthreads();
  if (wv == 0) {
    unsigned t = (lane < 16) ? wsum[lane] : 0u;
    unsigned vv = t;
#pragma unroll
    for (int off = 1; off < 16; off <<= 1) {
      unsigned u = __shfl_up(vv, off, 64);
      if (lane >= off) vv += u;
    }
    if (lane < 16) wsum[lane] = vv - t;            // exclusive
  }
  __syncthreads();
  unsigned b = wsum[wv] + v - s;
  cstart[tid*4+0] = b; cursor[tid*4+0] = b; b += c0;
  cstart[tid*4+1] = b; cursor[tid*4+1] = b; b += c1;
  cstart[tid*4+2] = b; cursor[tid*4+2] = b; b += c2;
  cstart[tid*4+3] = b; cursor[tid*4+3] = b; b += c3;
  if (tid == 1023) cstart[NCELL] = b;              // == NN
}

// ---------------------------------------------------------------- scatter into cell order
__global__ __launch_bounds__(256) void scatter_kernel(const float4* __restrict__ pack,
                                                      const unsigned* __restrict__ cellid,
                                                      unsigned* __restrict__ cursor,
                                                      float4* __restrict__ sorted,
                                                      int* __restrict__ sid) {
  int i = blockIdx.x * 256 + threadIdx.x;
  if (i >= NN) return;
  unsigned p = atomicAdd(&cursor[cellid[i]], 1u);
  sorted[p] = pack[i];                             // .w carries original index bits
  sid[p] = i;
}

// ---------------------------------------------------------------- knn (flat-scan) + gemm1 backfill
// R5 post-mortem: the knn wall (~43us) is span-boundary serialization -- each
// short span (rect row / ring cell) eats a full load latency with nothing in
// flight; invariant to lanes/node (R1), pipeline depth (R2), placement (R4),
// code size (R5). This version scans a FIXED 7x7 rect (R=3) as ONE flat
// candidate stream: all 14 row bounds prefetched at once, flat index mapped
// to address via static unrolled selects (no runtime indexing -> no scratch),
// 8-deep double-buffered load pipeline. Candidate set = 7x7 rect, a superset
// of the old 5x5+rings-to-R3; top-16 selection is scan-order/superset
// independent (exact keys, unique via index bits) and the validated
// count-based stop test then guarantees exactness; rare unfinished nodes
// fall back to the R5-proven ring expansion. Results bit-identical.
__global__ __launch_bounds__(256) void knn_gemm1_kernel(const float4* __restrict__ sorted,
                                                        const unsigned* __restrict__ cstart,
                                                        const float* __restrict__ c,
                                                        int* __restrict__ nbr,
                                                        float* __restrict__ de,
                                                        unsigned* __restrict__ gmm,
                                                        const float* __restrict__ xa_,
                                                        const float* __restrict__ w1,
                                                        float* __restrict__ xw1) {
#pragma clang fp contract(off)
  if (blockIdx.x >= KNNB) {
    // ---- gemm1: xw1 = x @ W1, KIN=32, 4 features/thread (R1-verbatim, proven)
    int gid = (blockIdx.x - KNNB) * 256 + threadIdx.x;   // NN*16 total
    int i = gid >> 4, fq = gid & 15;
    const float4* ar = (const float4*)(xa_ + i * FIN);
    float4 A[FIN/4];
#pragma unroll
    for (int qq = 0; qq < FIN/4; ++qq) A[qq] = ar[qq];
    float4 acc = make_float4(0.f, 0.f, 0.f, 0.f);
#pragma unroll
    for (int k = 0; k < FIN; ++k) {
      float av = ((const float*)A)[k];
      float4 wv4 = *(const float4*)(w1 + k*HH + 4*fq);
      acc.x = fmaf(av, wv4.x, acc.x);
      acc.y = fmaf(av, wv4.y, acc.y);
      acc.z = fmaf(av, wv4.z, acc.z);
      acc.w = fmaf(av, wv4.w, acc.w);
    }
    *(float4*)(xw1 + i*HH + 4*fq) = acc;
    return;
  }

  const int g = blockIdx.x * 256 + threadIdx.x;
  const int t = g >> 2;                            // sorted node index
  const int q = g & 3;                             // quad lane
  const int lane = threadIdx.x & 63;
  const float4 me = sorted[t];
  const int myid = (int)__float_as_uint(me.w);
  const float h = 1.0f / GG;                       // exact 2^-6
  int cx = (int)(me.x * GG); cx = cx > GG-1 ? GG-1 : (cx < 0 ? 0 : cx);
  int cy = (int)(me.y * GG); cy = cy > GG-1 ? GG-1 : (cy < 0 ? 0 : cy);

  unsigned long long kd[KK];
#pragma unroll
  for (int m = 0; m < KK; ++m) kd[m] = ~0ull;

  auto process = [&](float4 cand) {
    int j = (int)__float_as_uint(cand.w);
    float xprod = me.x * cand.x;                       // round(x_i*x_j)
    float dot   = __builtin_fmaf(me.y, cand.y, xprod); // BLAS K=2 fma
    float S     = me.z + cand.z;                       // round(sq_i+sq_j)
    float twod  = dot + dot;                           // exact *2
    float d2    = S - twod;                            // one rounding
    unsigned ub = __float_as_uint(d2);
    ub = (ub & 0x80000000u) ? ~ub : (ub | 0x80000000u);
    unsigned long long key = ((unsigned long long)ub << 32) | (unsigned)j;
    if (j != myid && key < kd[KK-1]) {
      unsigned long long ck = key;
#pragma unroll
      for (int m = 0; m < KK; ++m) {
        bool sw = ck < kd[m];
        unsigned long long lo = sw ? ck : kd[m];
        unsigned long long hi = sw ? kd[m] : ck;
        kd[m] = lo; ck = hi;
      }
    }
  };

  // ---- flat 7x7 rect scan (R=3): one pipelined candidate stream
  int lxa = cx-3 < 0 ? 0 : cx-3;
  int lxb = cx+3 > GG-1 ? GG-1 : cx+3;
  int lya = cy-3 < 0 ? 0 : cy-3;
  int lyb = cy+3 > GG-1 ? GG-1 : cy+3;
  unsigned rs[7], cum[8];
  {
    int nr = lyb - lya + 1;
    unsigned re_[7];
#pragma unroll
    for (int k = 0; k < 7; ++k) {
      if (k < nr) {
        rs[k]  = cstart[(lya+k)*GG + lxa];
        re_[k] = cstart[(lya+k)*GG + lxb + 1];
      } else { rs[k] = 0; re_[k] = 0; }
    }
    cum[0] = 0;
#pragma unroll
    for (int k = 0; k < 7; ++k) cum[k+1] = cum[k] + (re_[k] - rs[k]);
  }
  const unsigned T = cum[7];
  // flat idx -> global addr via static select chain (no runtime array index)
  auto addrOf = [&](unsigned i) -> unsigned {
    unsigned base = rs[0], coff = 0u;
#pragma unroll
    for (int k = 1; k < 7; ++k) {
      bool ge = i >= cum[k];
      base = ge ? rs[k] : base;
      coff = ge ? cum[k] : coff;
    }
    return base + (i - coff);
  };
  {
    float4 A[8];
#pragma unroll
    for (int d = 0; d < 8; ++d) {
      unsigned i = (unsigned)q + 4u*d;
      A[d] = make_float4(0.f, 0.f, 0.f, 0.f);
      if (i < T) A[d] = sorted[addrOf(i)];
    }
    unsigned iA = (unsigned)q;
#pragma unroll 1
    while (iA < T) {
      float4 B[8];
      unsigned iB = iA + 32u;
#pragma unroll
      for (int d = 0; d < 8; ++d) {
        unsigned i = iB + 4u*d;
        B[d] = make_float4(0.f, 0.f, 0.f, 0.f);
        if (i < T) B[d] = sorted[addrOf(i)];
      }
#pragma unroll
      for (int d = 0; d < 8; ++d) {
        unsigned i = iA + 4u*d;
        if (i < T) process(A[d]);
      }
#pragma unroll
      for (int d = 0; d < 8; ++d) A[d] = B[d];
      iA = iB;
    }
  }

  // ---- ring expansion with exact count-based stop (R5-proven, from R=3)
  // 2-deep pipelined span scan; instantiated at exactly 2 ring call sites
  auto scanSpan = [&](unsigned p0, unsigned p1) {
    unsigned pp = p0 + (unsigned)q;
    if (pp >= p1) return;
    float4 cur = sorted[pp];
    unsigned pn = pp + 4;
#pragma unroll 1
    while (pn < p1) {
      float4 nxt = sorted[pn];
      process(cur);
      cur = nxt;
      pn += 4;
    }
    process(cur);
  };
  int R = 3;
  while (true) {
    bool whole = (lxa <= 0) && (lxb >= GG-1) && (lya <= 0) && (lyb >= GG-1);
    bool done = whole;
    if (!done) {
      float edge = 1e30f;
      if (lxa > 0)    edge = fminf(edge, me.x - (float)lxa * h);
      if (lxb < GG-1) edge = fminf(edge, (float)(lxb+1) * h - me.x);
      if (lya > 0)    edge = fminf(edge, me.y - (float)lya * h);
      if (lyb < GG-1) edge = fminf(edge, (float)(lyb+1) * h - me.y);
      float lim = edge * edge - 1e-5f;             // margin >> Gram noise (~1e-6)
      if (lim > 0.0f) {
        unsigned lb = __float_as_uint(lim) | 0x80000000u;   // map(lim), lim>0
        int cle = 0;
#pragma unroll
        for (int m = 0; m < KK; ++m) cle += ((unsigned)(kd[m] >> 32) <= lb) ? 1 : 0;
        cle += __shfl_xor(cle, 1, 64);
        cle += __shfl_xor(cle, 2, 64);
        done = cle >= KK;
      }
    }
    if (done) break;
    ++R;
    int nxa = cx-R < 0 ? 0 : cx-R;
    int nxb = cx+R > GG-1 ? GG-1 : cx+R;
    int nya = cy-R < 0 ? 0 : cy-R;
    int nyb = cy+R > GG-1 ? GG-1 : cy+R;
    // new top/bottom rows (site 1)
#pragma unroll 1
    for (int rr = 0; rr < 2; ++rr) {
      int y = rr ? nyb : nya;
      bool has = rr ? (nyb > lyb) : (nya < lya);
      if (has) {
        unsigned p0 = cstart[y*GG + nxa];
        unsigned p1 = cstart[y*GG + nxb + 1];
        scanSpan(p0, p1);
      }
    }
    // new left/right columns (site 2): per-cell spans, bounds pipelined
#pragma unroll 1
    for (int ss = 0; ss < 2; ++ss) {
      int xcol = ss ? nxb : nxa;
      bool has = ss ? (nxb > lxb) : (nxa < lxa);
      if (has) {
        unsigned b0 = cstart[lya*GG + xcol];
        unsigned b1 = cstart[lya*GG + xcol + 1];
#pragma unroll 1
        for (int y = lya; y <= lyb; ++y) {
          unsigned n0 = 0, n1 = 0;
          if (y < lyb) { n0 = cstart[(y+1)*GG + xcol]; n1 = cstart[(y+1)*GG + xcol + 1]; }
          scanSpan(b0, b1);
          b0 = n0; b1 = n1;
        }
      }
    }
    lxa = nxa; lxb = nxb; lya = nya; lyb = nyb;
  }

  // ---- merge 4 sorted per-lane lists -> global top-16 (keys unique via j bits)
  unsigned res[4];
#pragma unroll 1
  for (int r = 0; r < KK; ++r) {
    unsigned long long md = kd[0];
    unsigned long long m1 = __shfl_xor(md, 1, 64); md = m1 < md ? m1 : md;
    unsigned long long m2 = __shfl_xor(md, 2, 64); md = m2 < md ? m2 : md;
    if (kd[0] == md) {                              // unique winner lane pops
#pragma unroll
      for (int m = 0; m < KK-1; ++m) kd[m] = kd[m+1];
      kd[KK-1] = ~0ull;
    }
    if ((r >> 2) == q) res[r & 3] = (unsigned)(md & 0xFFFFFFFFull);
  }

  // ---- write nbr + edge epilogue (identical ops to passing rounds)
  int4 w4; w4.x = (int)res[0]; w4.y = (int)res[1]; w4.z = (int)res[2]; w4.w = (int)res[3];
  *(int4*)(nbr + myid*KK + 4*q) = w4;
  unsigned bmin = 0xFFFFFFFFu, bmax = 0u;
#pragma unroll
  for (int e = 0; e < 4; ++e) {
    int j = (int)res[e];
    float dx = me.x - c[2*j];
    float dy = me.y - c[2*j+1];
    float xx = dx * dx;
    float yy = dy * dy;
    float d  = __builtin_sqrtf(xx + yy);
    de[myid*KK + 4*q + e] = d;
    unsigned bb = __float_as_uint(d);               // d >= 0: bit order == float order
    bmin = bmin < bb ? bmin : bb;
    bmax = bmax > bb ? bmax : bb;
  }
#pragma unroll
  for (int off = 32; off > 0; off >>= 1) {
    unsigned ob = __shfl_xor(bmin, off, 64);
    bmin = bmin < ob ? bmin : ob;
    unsigned oB = __shfl_xor(bmax, off, 64);
    bmax = bmax > oB ? bmax : oB;
  }
  if (lane == 0) {
    atomicMin(&gmm[0], bmin);
    atomicMax(&gmm[1], bmax);
  }
}

// ---------------------------------------------------------------- ew + deg + dis
__global__ __launch_bounds__(256) void ewdeg_kernel(const unsigned* __restrict__ gmm,
                                                    float* __restrict__ de,   // in: d, out: ew
                                                    float* __restrict__ dis) {
#pragma clang fp contract(off)
  int i = blockIdx.x * 256 + threadIdx.x;
  if (i >= NN) return;
  float mx  = __uint_as_float(gmm[1]);
  float rng = mx - __uint_as_float(gmm[0]);
  float deg = 0.0f;                         // edges first, self-loop last (segment_sum order)
  float4* dp = (float4*)(de + i*KK);
#pragma unroll
  for (int qq = 0; qq < 4; ++qq) {
    float4 v = dp[qq];
    float e0 = (mx - v.x) / rng;
    float e1 = (mx - v.y) / rng;
    float e2 = (mx - v.z) / rng;
    float e3 = (mx - v.w) / rng;
    deg = deg + e0; deg = deg + e1;
    deg = deg + e2; deg = deg + e3;
    dp[qq] = make_float4(e0, e1, e2, e3);
  }
  deg = deg + 1.0f;                         // self-loop weight 1, added last
  dis[i] = 1.0f / __builtin_sqrtf(deg);     // deg >= 1
}

// ---------------------------------------------------------------- agg1 + relu + gemm2 fused
// h1 row lives in registers (one float/lane); gemm2 via 64 shfl broadcasts,
// ascending-k fmaf order -> bit-identical xw2.
__global__ __launch_bounds__(256) void agg_gemm2_kernel(const float* __restrict__ xw,
                                                        const int* __restrict__ nbr,
                                                        const float* __restrict__ ew,
                                                        const float* __restrict__ dis,
                                                        const float* __restrict__ b,
                                                        const int* __restrict__ sid,
                                                        const float* __restrict__ w2,
                                                        float* __restrict__ xw2) {
  int wv = threadIdx.x >> 6, lane = threadIdx.x & 63;
  int i = sid[(blockIdx.x << 2) + wv];
  float di = dis[i];
  float acc = 0.0f;
#pragma unroll 4
  for (int k = 0; k < KK; ++k) {
    int s = nbr[i*KK + k];
    float coef = (dis[s] * ew[i*KK + k]) * di;   // (dis[s]*w)*dis[t]
    acc = fmaf(coef, xw[s*HH + lane], acc);
  }
  acc = fmaf(di * di, xw[i*HH + lane], acc);     // self loop last
  float hv = fmaxf(acc + b[lane], 0.0f);         // h1[i][lane]
  float acc2 = 0.0f;
#pragma unroll 16
  for (int k = 0; k < HH; ++k) {
    float hk = __shfl(hv, k, 64);
    acc2 = fmaf(hk, w2[k*HH + lane], acc2);
  }
  xw2[i*HH + lane] = acc2;
}

// ---------------------------------------------------------------- agg2 + relu + fc (final)
__global__ __launch_bounds__(256) void agg_fc_kernel(const float* __restrict__ xw,
                                                     const int* __restrict__ nbr,
                                                     const float* __restrict__ ew,
                                                     const float* __restrict__ dis,
                                                     const float* __restrict__ b,
                                                     const float* __restrict__ wfc,
                                                     const float* __restrict__ bfc,
                                                     const int* __restrict__ sid,
                                                     float* __restrict__ out) {
  int wv = threadIdx.x >> 6, lane = threadIdx.x & 63;
  int i = sid[(blockIdx.x << 2) + wv];
  float di = dis[i];
  float acc = 0.0f;
#pragma unroll 4
  for (int k = 0; k < KK; ++k) {
    int s = nbr[i*KK + k];
    float coef = (dis[s] * ew[i*KK + k]) * di;
    acc = fmaf(coef, xw[s*HH + lane], acc);
  }
  acc = fmaf(di * di, xw[i*HH + lane], acc);
  float v = fmaxf(acc + b[lane], 0.0f);             // h2 feature
  float p = v * wfc[lane];                          // h2 @ Wfc  (F_OUT = 1)
#pragma unroll
  for (int off = 32; off > 0; off >>= 1) p = p + __shfl_xor(p, off, 64);
  if (lane == 0) out[i] = p + bfc[0];
}

// ---------------------------------------------------------------- launch
extern "C" void kernel_launch(void* const* d_in, const int* in_sizes, int n_in,
                              void* d_out, int out_size, void* d_ws, size_t ws_size,
                              hipStream_t stream) {
  (void)in_sizes; (void)n_in; (void)out_size; (void)ws_size;
  const float* x   = (const float*)d_in[0];
  const float* c   = (const float*)d_in[1];
  const float* W1  = (const float*)d_in[2];
  const float* b1  = (const float*)d_in[3];
  const float* W2  = (const float*)d_in[4];
  const float* b2  = (const float*)d_in[5];
  const float* Wfc = (const float*)d_in[6];
  const float* bfc = (const float*)d_in[7];
  float* out = (float*)d_out;

  char* ws = (char*)d_ws;
  size_t off = 0;
  auto alloc = [&](size_t bytes) -> void* {
    void* p = ws + off;
    off += (bytes + 255) & ~size_t(255);
    return p;
  };
  float4*   pack   = (float4*)  alloc(NN * sizeof(float4));       // 256 KB
  float4*   sorted = (float4*)  alloc(NN * sizeof(float4));       // 256 KB
  unsigned* cnt    = (unsigned*)alloc(NCELL * sizeof(unsigned));  // 16 KB
  unsigned* cstart = (unsigned*)alloc((NCELL+1) * sizeof(unsigned));
  unsigned* cursor = (unsigned*)alloc(NCELL * sizeof(unsigned));
  unsigned* cellid = (unsigned*)alloc(NN * sizeof(unsigned));     // 64 KB
  int*      sid    = (int*)     alloc(NN * sizeof(int));          // 64 KB
  int*      nbr    = (int*)     alloc(NE * sizeof(int));          // 1 MB
  float*    ew     = (float*)   alloc(NE * sizeof(float));        // 1 MB (d then ew in-place)
  float*    dis    = (float*)   alloc(NN * sizeof(float));        // 64 KB
  unsigned* gmm    = (unsigned*)alloc(2 * sizeof(unsigned));
  float*    xw1    = (float*)   alloc(NN * HH * sizeof(float));   // 4 MB
  float*    xw2    = (float*)   alloc(NN * HH * sizeof(float));   // 4 MB

  const int NB = (NN + 255) / 256;
  hipMemsetAsync(cnt, 0, NCELL * sizeof(unsigned), stream);
  prep_count_kernel<<<NB,   256, 0, stream>>>(c, pack, cellid, cnt, gmm);
  scan_kernel      <<<1,   1024, 0, stream>>>(cnt, cstart, cursor);
  scatter_kernel   <<<NB,   256, 0, stream>>>(pack, cellid, cursor, sorted, sid);
  knn_gemm1_kernel <<<KNNB + GEMM1B, 256, 0, stream>>>(sorted, cstart, c, nbr, ew, gmm,
                                                       x, W1, xw1);
  ewdeg_kernel     <<<NB,   256, 0, stream>>>(gmm, ew, dis);
  agg_gemm2_kernel <<<NN/4, 256, 0, stream>>>(xw1, nbr, ew, dis, b1, sid, W2, xw2);
  agg_fc_kernel    <<<NN/4, 256, 0, stream>>>(xw2, nbr, ew, dis, b2, Wfc, bfc, sid, out);
}

// Round 7
// 156.300 us; speedup vs baseline: 1.1811x; 1.0942x over previous
//
#include <hip/hip_runtime.h>
#include <cstdint>

#define NN 16000
#define KK 16
#define FIN 32
#define HH 64
#define NE (NN*KK)
#define GG 32                    // R6 post-mortem: 15.6 pts/cell -> 3x3 rect
                                 // gives stop-radius lambda~49 >> 16: rings ~never
#define NCELL (GG*GG)

#define KNNB 250                 // knn blocks: 64 nodes/block (4 lanes/node)
#define GEMM1B (NN*16/256)       // 1000 gemm1 blocks

// ---------------------------------------------------------------- prep + count
__global__ __launch_bounds__(256) void prep_count_kernel(const float* __restrict__ c,
                                                         float4* __restrict__ pack,
                                                         unsigned* __restrict__ cellid,
                                                         unsigned* __restrict__ cnt,
                                                         unsigned* __restrict__ gmm) {
#pragma clang fp contract(off)
  int i = blockIdx.x * 256 + threadIdx.x;
  if (i == 0) { gmm[0] = 0x7F800000u; gmm[1] = 0u; }  // min=+inf bits, max=0 (d>=0)
  if (i >= NN) return;
  float xv = c[2*i], yv = c[2*i+1];
  float xx = xv * xv;            // round(x^2)  (no fma: contract off)
  float yy = yv * yv;            // round(y^2)
  float sq = xx + yy;            // round(xx+yy)
  pack[i] = make_float4(xv, yv, sq, __uint_as_float((unsigned)i));
  int cx = (int)(xv * GG); cx = cx > GG-1 ? GG-1 : (cx < 0 ? 0 : cx);
  int cy = (int)(yv * GG); cy = cy > GG-1 ? GG-1 : (cy < 0 ? 0 : cy);
  unsigned cell = (unsigned)(cy * GG + cx);
  cellid[i] = cell;
  atomicAdd(&cnt[cell], 1u);
}

// ---------------------------------------------------------------- prefix scan (single block, 1024 cells, 1/thread)
__global__ __launch_bounds__(1024) void scan_kernel(const unsigned* __restrict__ cnt,
                                                    unsigned* __restrict__ cstart,
                                                    unsigned* __restrict__ cursor) {
  __shared__ unsigned wsum[16];
  int tid = threadIdx.x;
  int lane = tid & 63, wv = tid >> 6;
  unsigned c0 = cnt[tid];
  unsigned v = c0;
#pragma unroll
  for (int off = 1; off < 64; off <<= 1) {
    unsigned u = __shfl_up(v, off, 64);
    if (lane >= off) v += u;
  }
  if (lane == 63) wsum[wv] = v;
  __syncthreads();
  if (wv == 0) {
    unsigned t = (lane < 16) ? wsum[lane] : 0u;
    unsigned vv = t;
#pragma unroll
    for (int off = 1; off < 16; off <<= 1) {
      unsigned u = __shfl_up(vv, off, 64);
      if (lane >= off) vv += u;
    }
    if (lane < 16) wsum[lane] = vv - t;            // exclusive
  }
  __syncthreads();
  unsigned b = wsum[wv] + v - c0;                  // exclusive prefix
  cstart[tid] = b; cursor[tid] = b;
  if (tid == 1023) cstart[NCELL] = b + c0;         // == NN
}

// ---------------------------------------------------------------- scatter into cell order
__global__ __launch_bounds__(256) void scatter_kernel(const float4* __restrict__ pack,
                                                      const unsigned* __restrict__ cellid,
                                                      unsigned* __restrict__ cursor,
                                                      float4* __restrict__ sorted,
                                                      int* __restrict__ sid) {
  int i = blockIdx.x * 256 + threadIdx.x;
  if (i >= NN) return;
  unsigned p = atomicAdd(&cursor[cellid[i]], 1u);
  sorted[p] = pack[i];                             // .w carries original index bits
  sid[p] = i;
}

// ---------------------------------------------------------------- knn (GG=32, 3x3 rect) + gemm1 backfill
// R6 post-mortem: with GG=64 the post-rect stop radius held only ~12 expected
// neighbors (<16), so MOST nodes took the ring path: 12+ extra short serial
// spans, each a fully-exposed load latency at 1 wave/SIMD. That was the
// invariant ~43us. GG=32 + 3x3 rect puts ~49 expected neighbors inside the
// guaranteed stop radius -> rings essentially never fire; the chain is 3
// row-spans + one stop test. Code is the R5-proven lean span-scan (3 call
// sites); stop proof is generic in h=1/GG; selection is scan-set independent
// (exact keys, index tie-break) -> results bit-identical.
__global__ __launch_bounds__(256) void knn_gemm1_kernel(const float4* __restrict__ sorted,
                                                        const unsigned* __restrict__ cstart,
                                                        const float* __restrict__ c,
                                                        int* __restrict__ nbr,
                                                        float* __restrict__ de,
                                                        unsigned* __restrict__ gmm,
                                                        const float* __restrict__ xa_,
                                                        const float* __restrict__ w1,
                                                        float* __restrict__ xw1) {
#pragma clang fp contract(off)
  if (blockIdx.x >= KNNB) {
    // ---- gemm1: xw1 = x @ W1, KIN=32, 4 features/thread (R1-verbatim, proven)
    int gid = (blockIdx.x - KNNB) * 256 + threadIdx.x;   // NN*16 total
    int i = gid >> 4, fq = gid & 15;
    const float4* ar = (const float4*)(xa_ + i * FIN);
    float4 A[FIN/4];
#pragma unroll
    for (int qq = 0; qq < FIN/4; ++qq) A[qq] = ar[qq];
    float4 acc = make_float4(0.f, 0.f, 0.f, 0.f);
#pragma unroll
    for (int k = 0; k < FIN; ++k) {
      float av = ((const float*)A)[k];
      float4 wv4 = *(const float4*)(w1 + k*HH + 4*fq);
      acc.x = fmaf(av, wv4.x, acc.x);
      acc.y = fmaf(av, wv4.y, acc.y);
      acc.z = fmaf(av, wv4.z, acc.z);
      acc.w = fmaf(av, wv4.w, acc.w);
    }
    *(float4*)(xw1 + i*HH + 4*fq) = acc;
    return;
  }

  const int g = blockIdx.x * 256 + threadIdx.x;
  const int t = g >> 2;                            // sorted node index
  const int q = g & 3;                             // quad lane
  const int lane = threadIdx.x & 63;
  const float4 me = sorted[t];
  const int myid = (int)__float_as_uint(me.w);
  const float h = 1.0f / GG;                       // exact 2^-5
  int cx = (int)(me.x * GG); cx = cx > GG-1 ? GG-1 : (cx < 0 ? 0 : cx);
  int cy = (int)(me.y * GG); cy = cy > GG-1 ? GG-1 : (cy < 0 ? 0 : cy);

  unsigned long long kd[KK];
#pragma unroll
  for (int m = 0; m < KK; ++m) kd[m] = ~0ull;

  auto process = [&](float4 cand) {
    int j = (int)__float_as_uint(cand.w);
    float xprod = me.x * cand.x;                       // round(x_i*x_j)
    float dot   = __builtin_fmaf(me.y, cand.y, xprod); // BLAS K=2 fma
    float S     = me.z + cand.z;                       // round(sq_i+sq_j)
    float twod  = dot + dot;                           // exact *2
    float d2    = S - twod;                            // one rounding
    unsigned ub = __float_as_uint(d2);
    ub = (ub & 0x80000000u) ? ~ub : (ub | 0x80000000u);
    unsigned long long key = ((unsigned long long)ub << 32) | (unsigned)j;
    if (j != myid && key < kd[KK-1]) {
      unsigned long long ck = key;
#pragma unroll
      for (int m = 0; m < KK; ++m) {
        bool sw = ck < kd[m];
        unsigned long long lo = sw ? ck : kd[m];
        unsigned long long hi = sw ? kd[m] : ck;
        kd[m] = lo; ck = hi;
      }
    }
  };
  // 2-deep pipelined span scan; instantiated at exactly 3 call sites
  auto scanSpan = [&](unsigned p0, unsigned p1) {
    unsigned pp = p0 + (unsigned)q;
    if (pp >= p1) return;
    float4 cur = sorted[pp];
    unsigned pn = pp + 4;
#pragma unroll 1
    while (pn < p1) {
      float4 nxt = sorted[pn];
      process(cur);
      cur = nxt;
      pn += 4;
    }
    process(cur);
  };

  // ---- initial 3x3 rect (site 1): row bounds software-pipelined
  int lxa = cx-1 < 0 ? 0 : cx-1;
  int lxb = cx+1 > GG-1 ? GG-1 : cx+1;
  int lya = cy-1 < 0 ? 0 : cy-1;
  int lyb = cy+1 > GG-1 ? GG-1 : cy+1;
  {
    unsigned b0 = cstart[lya*GG + lxa];
    unsigned b1 = cstart[lya*GG + lxb + 1];
#pragma unroll 1
    for (int y = lya; y <= lyb; ++y) {
      unsigned n0 = 0, n1 = 0;
      if (y < lyb) { n0 = cstart[(y+1)*GG + lxa]; n1 = cstart[(y+1)*GG + lxb + 1]; }
      scanSpan(b0, b1);
      b0 = n0; b1 = n1;
    }
  }

  // ---- ring expansion with exact count-based stop (validated; generic in h)
  int R = 1;
  while (true) {
    bool whole = (lxa <= 0) && (lxb >= GG-1) && (lya <= 0) && (lyb >= GG-1);
    bool done = whole;
    if (!done) {
      float edge = 1e30f;
      if (lxa > 0)    edge = fminf(edge, me.x - (float)lxa * h);
      if (lxb < GG-1) edge = fminf(edge, (float)(lxb+1) * h - me.x);
      if (lya > 0)    edge = fminf(edge, me.y - (float)lya * h);
      if (lyb < GG-1) edge = fminf(edge, (float)(lyb+1) * h - me.y);
      float lim = edge * edge - 1e-5f;             // margin >> Gram noise (~1e-6)
      if (lim > 0.0f) {
        unsigned lb = __float_as_uint(lim) | 0x80000000u;   // map(lim), lim>0
        int cle = 0;
#pragma unroll
        for (int m = 0; m < KK; ++m) cle += ((unsigned)(kd[m] >> 32) <= lb) ? 1 : 0;
        cle += __shfl_xor(cle, 1, 64);
        cle += __shfl_xor(cle, 2, 64);
        done = cle >= KK;
      }
    }
    if (done) break;
    ++R;
    int nxa = cx-R < 0 ? 0 : cx-R;
    int nxb = cx+R > GG-1 ? GG-1 : cx+R;
    int nya = cy-R < 0 ? 0 : cy-R;
    int nyb = cy+R > GG-1 ? GG-1 : cy+R;
    // new top/bottom rows (site 2)
#pragma unroll 1
    for (int rr = 0; rr < 2; ++rr) {
      int y = rr ? nyb : nya;
      bool has = rr ? (nyb > lyb) : (nya < lya);
      if (has) {
        unsigned p0 = cstart[y*GG + nxa];
        unsigned p1 = cstart[y*GG + nxb + 1];
        scanSpan(p0, p1);
      }
    }
    // new left/right columns (site 3): per-cell spans, bounds pipelined
#pragma unroll 1
    for (int ss = 0; ss < 2; ++ss) {
      int xcol = ss ? nxb : nxa;
      bool has = ss ? (nxb > lxb) : (nxa < lxa);
      if (has) {
        unsigned b0 = cstart[lya*GG + xcol];
        unsigned b1 = cstart[lya*GG + xcol + 1];
#pragma unroll 1
        for (int y = lya; y <= lyb; ++y) {
          unsigned n0 = 0, n1 = 0;
          if (y < lyb) { n0 = cstart[(y+1)*GG + xcol]; n1 = cstart[(y+1)*GG + xcol + 1]; }
          scanSpan(b0, b1);
          b0 = n0; b1 = n1;
        }
      }
    }
    lxa = nxa; lxb = nxb; lya = nya; lyb = nyb;
  }

  // ---- merge 4 sorted per-lane lists -> global top-16 (keys unique via j bits)
  unsigned res[4];
#pragma unroll 1
  for (int r = 0; r < KK; ++r) {
    unsigned long long md = kd[0];
    unsigned long long m1 = __shfl_xor(md, 1, 64); md = m1 < md ? m1 : md;
    unsigned long long m2 = __shfl_xor(md, 2, 64); md = m2 < md ? m2 : md;
    if (kd[0] == md) {                              // unique winner lane pops
#pragma unroll
      for (int m = 0; m < KK-1; ++m) kd[m] = kd[m+1];
      kd[KK-1] = ~0ull;
    }
    if ((r >> 2) == q) res[r & 3] = (unsigned)(md & 0xFFFFFFFFull);
  }

  // ---- write nbr + edge epilogue (identical ops to passing rounds)
  int4 w4; w4.x = (int)res[0]; w4.y = (int)res[1]; w4.z = (int)res[2]; w4.w = (int)res[3];
  *(int4*)(nbr + myid*KK + 4*q) = w4;
  unsigned bmin = 0xFFFFFFFFu, bmax = 0u;
#pragma unroll
  for (int e = 0; e < 4; ++e) {
    int j = (int)res[e];
    float dx = me.x - c[2*j];
    float dy = me.y - c[2*j+1];
    float xx = dx * dx;
    float yy = dy * dy;
    float d  = __builtin_sqrtf(xx + yy);
    de[myid*KK + 4*q + e] = d;
    unsigned bb = __float_as_uint(d);               // d >= 0: bit order == float order
    bmin = bmin < bb ? bmin : bb;
    bmax = bmax > bb ? bmax : bb;
  }
#pragma unroll
  for (int off = 32; off > 0; off >>= 1) {
    unsigned ob = __shfl_xor(bmin, off, 64);
    bmin = bmin < ob ? bmin : ob;
    unsigned oB = __shfl_xor(bmax, off, 64);
    bmax = bmax > oB ? bmax : oB;
  }
  if (lane == 0) {
    atomicMin(&gmm[0], bmin);
    atomicMax(&gmm[1], bmax);
  }
}

// ---------------------------------------------------------------- ew + deg + dis
__global__ __launch_bounds__(256) void ewdeg_kernel(const unsigned* __restrict__ gmm,
                                                    float* __restrict__ de,   // in: d, out: ew
                                                    float* __restrict__ dis) {
#pragma clang fp contract(off)
  int i = blockIdx.x * 256 + threadIdx.x;
  if (i >= NN) return;
  float mx  = __uint_as_float(gmm[1]);
  float rng = mx - __uint_as_float(gmm[0]);
  float deg = 0.0f;                         // edges first, self-loop last (segment_sum order)
  float4* dp = (float4*)(de + i*KK);
#pragma unroll
  for (int qq = 0; qq < 4; ++qq) {
    float4 v = dp[qq];
    float e0 = (mx - v.x) / rng;
    float e1 = (mx - v.y) / rng;
    float e2 = (mx - v.z) / rng;
    float e3 = (mx - v.w) / rng;
    deg = deg + e0; deg = deg + e1;
    deg = deg + e2; deg = deg + e3;
    dp[qq] = make_float4(e0, e1, e2, e3);
  }
  deg = deg + 1.0f;                         // self-loop weight 1, added last
  dis[i] = 1.0f / __builtin_sqrtf(deg);     // deg >= 1
}

// ---------------------------------------------------------------- agg1 + relu + gemm2 fused
// h1 row lives in registers (one float/lane); gemm2 via 64 shfl broadcasts,
// ascending-k fmaf order -> bit-identical xw2.
__global__ __launch_bounds__(256) void agg_gemm2_kernel(const float* __restrict__ xw,
                                                        const int* __restrict__ nbr,
                                                        const float* __restrict__ ew,
                                                        const float* __restrict__ dis,
                                                        const float* __restrict__ b,
                                                        const int* __restrict__ sid,
                                                        const float* __restrict__ w2,
                                                        float* __restrict__ xw2) {
  int wv = threadIdx.x >> 6, lane = threadIdx.x & 63;
  int i = sid[(blockIdx.x << 2) + wv];
  float di = dis[i];
  float acc = 0.0f;
#pragma unroll 4
  for (int k = 0; k < KK; ++k) {
    int s = nbr[i*KK + k];
    float coef = (dis[s] * ew[i*KK + k]) * di;   // (dis[s]*w)*dis[t]
    acc = fmaf(coef, xw[s*HH + lane], acc);
  }
  acc = fmaf(di * di, xw[i*HH + lane], acc);     // self loop last
  float hv = fmaxf(acc + b[lane], 0.0f);         // h1[i][lane]
  float acc2 = 0.0f;
#pragma unroll 16
  for (int k = 0; k < HH; ++k) {
    float hk = __shfl(hv, k, 64);
    acc2 = fmaf(hk, w2[k*HH + lane], acc2);
  }
  xw2[i*HH + lane] = acc2;
}

// ---------------------------------------------------------------- agg2 + relu + fc (final)
__global__ __launch_bounds__(256) void agg_fc_kernel(const float* __restrict__ xw,
                                                     const int* __restrict__ nbr,
                                                     const float* __restrict__ ew,
                                                     const float* __restrict__ dis,
                                                     const float* __restrict__ b,
                                                     const float* __restrict__ wfc,
                                                     const float* __restrict__ bfc,
                                                     const int* __restrict__ sid,
                                                     float* __restrict__ out) {
  int wv = threadIdx.x >> 6, lane = threadIdx.x & 63;
  int i = sid[(blockIdx.x << 2) + wv];
  float di = dis[i];
  float acc = 0.0f;
#pragma unroll 4
  for (int k = 0; k < KK; ++k) {
    int s = nbr[i*KK + k];
    float coef = (dis[s] * ew[i*KK + k]) * di;
    acc = fmaf(coef, xw[s*HH + lane], acc);
  }
  acc = fmaf(di * di, xw[i*HH + lane], acc);
  float v = fmaxf(acc + b[lane], 0.0f);             // h2 feature
  float p = v * wfc[lane];                          // h2 @ Wfc  (F_OUT = 1)
#pragma unroll
  for (int off = 32; off > 0; off >>= 1) p = p + __shfl_xor(p, off, 64);
  if (lane == 0) out[i] = p + bfc[0];
}

// ---------------------------------------------------------------- launch
extern "C" void kernel_launch(void* const* d_in, const int* in_sizes, int n_in,
                              void* d_out, int out_size, void* d_ws, size_t ws_size,
                              hipStream_t stream) {
  (void)in_sizes; (void)n_in; (void)out_size; (void)ws_size;
  const float* x   = (const float*)d_in[0];
  const float* c   = (const float*)d_in[1];
  const float* W1  = (const float*)d_in[2];
  const float* b1  = (const float*)d_in[3];
  const float* W2  = (const float*)d_in[4];
  const float* b2  = (const float*)d_in[5];
  const float* Wfc = (const float*)d_in[6];
  const float* bfc = (const float*)d_in[7];
  float* out = (float*)d_out;

  char* ws = (char*)d_ws;
  size_t off = 0;
  auto alloc = [&](size_t bytes) -> void* {
    void* p = ws + off;
    off += (bytes + 255) & ~size_t(255);
    return p;
  };
  float4*   pack   = (float4*)  alloc(NN * sizeof(float4));       // 256 KB
  float4*   sorted = (float4*)  alloc(NN * sizeof(float4));       // 256 KB
  unsigned* cnt    = (unsigned*)alloc(NCELL * sizeof(unsigned));  // 4 KB
  unsigned* cstart = (unsigned*)alloc((NCELL+1) * sizeof(unsigned));
  unsigned* cursor = (unsigned*)alloc(NCELL * sizeof(unsigned));
  unsigned* cellid = (unsigned*)alloc(NN * sizeof(unsigned));     // 64 KB
  int*      sid    = (int*)     alloc(NN * sizeof(int));          // 64 KB
  int*      nbr    = (int*)     alloc(NE * sizeof(int));          // 1 MB
  float*    ew     = (float*)   alloc(NE * sizeof(float));        // 1 MB (d then ew in-place)
  float*    dis    = (float*)   alloc(NN * sizeof(float));        // 64 KB
  unsigned* gmm    = (unsigned*)alloc(2 * sizeof(unsigned));
  float*    xw1    = (float*)   alloc(NN * HH * sizeof(float));   // 4 MB
  float*    xw2    = (float*)   alloc(NN * HH * sizeof(float));   // 4 MB

  const int NB = (NN + 255) / 256;
  hipMemsetAsync(cnt, 0, NCELL * sizeof(unsigned), stream);
  prep_count_kernel<<<NB,   256, 0, stream>>>(c, pack, cellid, cnt, gmm);
  scan_kernel      <<<1,   1024, 0, stream>>>(cnt, cstart, cursor);
  scatter_kernel   <<<NB,   256, 0, stream>>>(pack, cellid, cursor, sorted, sid);
  knn_gemm1_kernel <<<KNNB + GEMM1B, 256, 0, stream>>>(sorted, cstart, c, nbr, ew, gmm,
                                                       x, W1, xw1);
  ewdeg_kernel     <<<NB,   256, 0, stream>>>(gmm, ew, dis);
  agg_gemm2_kernel <<<NN/4, 256, 0, stream>>>(xw1, nbr, ew, dis, b1, sid, W2, xw2);
  agg_fc_kernel    <<<NN/4, 256, 0, stream>>>(xw2, nbr, ew, dis, b2, Wfc, bfc, sid, out);
}